// Round 6
// baseline (525.249 us; speedup 1.0000x reference)
//
#include <hip/hip_runtime.h>
#include <math.h>

#define S_LEN 2048
#define INNERD 2048
#define NHEAD 4
#define DHEAD 512
#define BATCH 2
#define SCALE_QK 0.044194173824159216f

typedef __attribute__((ext_vector_type(8))) short short8v;
typedef __attribute__((ext_vector_type(4))) float f32x4;

#define MFMA_BF16(A, B, C) __builtin_amdgcn_mfma_f32_16x16x32_bf16(A, B, C, 0, 0, 0)

__device__ __forceinline__ void gll16(const void* g, void* l) {
  __builtin_amdgcn_global_load_lds((const __attribute__((address_space(1))) unsigned int*)g,
                                   (__attribute__((address_space(3))) unsigned int*)l,
                                   16, 0, 0);
}

__device__ __forceinline__ unsigned short f2bf(float x) {
  union { float f; unsigned u; } v; v.f = x;
  unsigned r = v.u + 0x7FFFu + ((v.u >> 16) & 1u);
  return (unsigned short)(r >> 16);
}
__device__ __forceinline__ float bf2f(unsigned short x) {
  union { unsigned u; float f; } v; v.u = ((unsigned)x) << 16; return v.f;
}
__device__ __forceinline__ float swishf(float x) { return x / (1.0f + __expf(-x)); }
__device__ __forceinline__ float logsigf(float x) {
  return (x >= 0.0f) ? -log1pf(expf(-x)) : (x - log1pf(expf(x)));
}

// ---------------- cast f32 -> bf16 (8 elems/thread) ----------------
__global__ __launch_bounds__(256) void cast_kernel(const float* __restrict__ src,
                                                   unsigned short* __restrict__ dst) {
  const int i = (blockIdx.x * 256 + threadIdx.x) * 8;
  const float4 a = *(const float4*)(src + i);
  const float4 b = *(const float4*)(src + i + 4);
  short8v o;
  o[0] = (short)f2bf(a.x); o[1] = (short)f2bf(a.y); o[2] = (short)f2bf(a.z); o[3] = (short)f2bf(a.w);
  o[4] = (short)f2bf(b.x); o[5] = (short)f2bf(b.y); o[6] = (short)f2bf(b.z); o[7] = (short)f2bf(b.w);
  *(short8v*)(dst + i) = o;
}

// ------------- transpose+cast weights: f32 [R][C] -> bf16 [C][R] -------------
__global__ __launch_bounds__(256) void trc_kernel(const float* __restrict__ src,
                                                  unsigned short* __restrict__ dst,
                                                  int R, int C) {
  const int t = threadIdx.x;
  const int r0 = blockIdx.y * 128, c0 = blockIdx.x * 128;
  const int rb = (t >> 4) * 8, cb2 = (t & 15) * 8;
  float vreg[8][8];
#pragma unroll
  for (int u = 0; u < 8; ++u) {
    const float4 p0 = *(const float4*)(src + (size_t)(r0 + rb + u) * C + c0 + cb2);
    const float4 p1 = *(const float4*)(src + (size_t)(r0 + rb + u) * C + c0 + cb2 + 4);
    vreg[u][0] = p0.x; vreg[u][1] = p0.y; vreg[u][2] = p0.z; vreg[u][3] = p0.w;
    vreg[u][4] = p1.x; vreg[u][5] = p1.y; vreg[u][6] = p1.z; vreg[u][7] = p1.w;
  }
#pragma unroll
  for (int j = 0; j < 8; ++j) {
    short8v o;
#pragma unroll
    for (int u = 0; u < 8; ++u) o[u] = (short)f2bf(vreg[u][j]);
    *(short8v*)(dst + (size_t)(c0 + cb2 + j) * R + r0 + rb) = o;
  }
}

// ------------- v bf16 [4096][2048] -> vT bf16 [8][512][2048] -------------
__global__ __launch_bounds__(256) void trv_kernel(const unsigned short* __restrict__ v,
                                                  unsigned short* __restrict__ vt) {
  const int t = threadIdx.x;
  const int s0 = blockIdx.x * 128;
  const int d0 = blockIdx.y * 128;
  const int bn = blockIdx.z;
  const int b = bn >> 2, n = bn & 3;
  const int sb = (t >> 4) * 8, db = (t & 15) * 8;
  unsigned short r[8][8];
#pragma unroll
  for (int u = 0; u < 8; ++u) {
    const short8v x2 = *(const short8v*)(v + (size_t)(b * S_LEN + s0 + sb + u) * INNERD + n * DHEAD + d0 + db);
#pragma unroll
    for (int j = 0; j < 8; ++j) r[u][j] = (unsigned short)x2[j];
  }
#pragma unroll
  for (int j = 0; j < 8; ++j) {
    short8v o;
#pragma unroll
    for (int u = 0; u < 8; ++u) o[u] = (short)r[u][j];
    *(short8v*)(vt + (size_t)(bn * DHEAD + d0 + db + j) * S_LEN + s0 + sb) = o;
  }
}

// ------- prep: pack qkv weights bf16 per-thread + fold gate weights (transposed bf16) -------
__global__ __launch_bounds__(256) void prep_kernel(
    const float* __restrict__ Wq, const float* __restrict__ Wk, const float* __restrict__ Wv,
    const float* __restrict__ Wig, const float* __restrict__ Wfg,
    unsigned short* __restrict__ Wpk, unsigned short* __restrict__ CgT) {
  const int t = threadIdx.x;
  float wq[2][16], wk[2][16], wv[2][16];
#pragma unroll
  for (int hh = 0; hh < 2; ++hh) {
    const int h = 2 * t + hh;
#pragma unroll
    for (int j = 0; j < 16; ++j) {
      wq[hh][j] = Wq[(size_t)h * 16 + j];
      wk[hh][j] = Wk[(size_t)h * 16 + j];
      wv[hh][j] = Wv[(size_t)h * 16 + j];
    }
  }
#pragma unroll
  for (int hh = 0; hh < 2; ++hh)
#pragma unroll
    for (int sub = 0; sub < 2; ++sub) {
      short8v oq, ok, ov;
#pragma unroll
      for (int j = 0; j < 8; ++j) {
        oq[j] = (short)f2bf(wq[hh][sub * 8 + j]);
        ok[j] = (short)f2bf(wk[hh][sub * 8 + j]);
        ov[j] = (short)f2bf(wv[hh][sub * 8 + j]);
      }
      *(short8v*)(Wpk + ((size_t)(0 + hh * 2 + sub) * 256 + t) * 8) = oq;
      *(short8v*)(Wpk + ((size_t)(4 + hh * 2 + sub) * 256 + t) * 8) = ok;
      *(short8v*)(Wpk + ((size_t)(8 + hh * 2 + sub) * 256 + t) * 8) = ov;
    }
#pragma unroll
  for (int u = 0; u < 8; ++u) {
    const int hh = u >> 2, d = u & 3;
    const int h = 2 * t + hh;
    float cia[4] = {0, 0, 0, 0}, cim[4] = {0, 0, 0, 0};
    float cfa[4] = {0, 0, 0, 0}, cfm[4] = {0, 0, 0, 0};
#pragma unroll
    for (int o = 0; o < 4; ++o) {
      const int row = h * 4 + o;
      const float aq = wq[hh][o * 4 + d], ak = wk[hh][o * 4 + d], av = wv[hh][o * 4 + d];
#pragma unroll
      for (int g = 0; g < 4; ++g) {
        cia[g] += aq * Wig[(size_t)row * 4 + g] + ak * Wig[(size_t)(INNERD + row) * 4 + g];
        cim[g] += av * Wig[(size_t)(2 * INNERD + row) * 4 + g];
        cfa[g] += aq * Wfg[(size_t)row * 4 + g] + ak * Wfg[(size_t)(INNERD + row) * 4 + g];
        cfm[g] += av * Wfg[(size_t)(2 * INNERD + row) * 4 + g];
      }
    }
    const int c = t * 8 + u;
#pragma unroll
    for (int g = 0; g < 4; ++g) {
      CgT[(size_t)(g) * INNERD + c] = f2bf(cia[g]);
      CgT[(size_t)(4 + g) * INNERD + c] = f2bf(cim[g]);
      CgT[(size_t)(8 + g) * INNERD + c] = f2bf(cfa[g]);
      CgT[(size_t)(12 + g) * INNERD + c] = f2bf(cfm[g]);
    }
  }
}

// ---------------- bf16 MFMA GEMM: C[M,N] = A[M,K] * Bt[N,K]^T, tile 128xBN ----------------
template <int BN, int OUTMODE>
__global__ __launch_bounds__(256) void gemm_bf16(const unsigned short* __restrict__ A,
                                                 const unsigned short* __restrict__ Bt,
                                                 float* __restrict__ Cf,
                                                 unsigned short* __restrict__ Cb0,
                                                 unsigned short* __restrict__ Cb1,
                                                 int M, int N, int K) {
  constexpr int CB = BN / 32;
  __shared__ unsigned short As[128 * 64];
  __shared__ unsigned short Bs[BN * 64];
  const int tid = threadIdx.x;
  const int w = tid >> 6, l = tid & 63;
  const int lm = l & 15, l4 = l >> 4, l8 = l & 7, lr = l >> 3;
  const int nwg = gridDim.x * gridDim.y;
  int bid = blockIdx.y * gridDim.x + blockIdx.x;
  const int cpx = nwg >> 3;
  bid = (bid & 7) * cpx + (bid >> 3);  // XCD swizzle (nwg % 8 == 0)
  const int bx = bid % gridDim.x, by = bid / gridDim.x;
  const int row0 = by * 128, col0 = bx * BN;
  const int wm = w >> 1, wn = w & 1;
  f32x4 acc[4 * CB];
#pragma unroll
  for (int i2 = 0; i2 < 4 * CB; ++i2) acc[i2] = (f32x4){0.f, 0.f, 0.f, 0.f};

  const int scol = (l8 * 16) ^ (lr << 4);

  for (int k0 = 0; k0 < K; k0 += 64) {
#pragma unroll
    for (int it = 0; it < 4; ++it) {
      const int r = it * 32 + w * 8 + lr;
      gll16((const char*)A + ((size_t)(row0 + r) * K + k0) * 2 + scol,
            (char*)As + (size_t)(it * 32 + w * 8) * 128);
    }
#pragma unroll
    for (int it = 0; it < BN / 32; ++it) {
      const int r = it * 32 + w * 8 + lr;
      gll16((const char*)Bt + ((size_t)(col0 + r) * K + k0) * 2 + scol,
            (char*)Bs + (size_t)(it * 32 + w * 8) * 128);
    }
    __syncthreads();
#pragma unroll
    for (int ks = 0; ks < 2; ++ks) {
      short8v af[4], bfr[CB];
#pragma unroll
      for (int rb = 0; rb < 4; ++rb) {
        const int row = wm * 64 + rb * 16 + lm;
        af[rb] = *(const short8v*)((const char*)As + row * 128 + ((ks * 64 + l4 * 16) ^ ((lm & 7) << 4)));
      }
#pragma unroll
      for (int cb = 0; cb < CB; ++cb) {
        const int row = wn * (BN / 2) + cb * 16 + lm;
        bfr[cb] = *(const short8v*)((const char*)Bs + row * 128 + ((ks * 64 + l4 * 16) ^ ((lm & 7) << 4)));
      }
      __builtin_amdgcn_s_setprio(1);
#pragma unroll
      for (int rb = 0; rb < 4; ++rb)
#pragma unroll
        for (int cb = 0; cb < CB; ++cb)
          acc[rb * CB + cb] = MFMA_BF16(af[rb], bfr[cb], acc[rb * CB + cb]);
      __builtin_amdgcn_s_setprio(0);
    }
    __syncthreads();
  }
#pragma unroll
  for (int rb = 0; rb < 4; ++rb)
#pragma unroll
    for (int cb = 0; cb < CB; ++cb)
#pragma unroll
      for (int r = 0; r < 4; ++r) {
        const int gr = row0 + wm * 64 + rb * 16 + l4 * 4 + r;
        const int gc = col0 + wn * (BN / 2) + cb * 16 + lm;
        const float vv = acc[rb * CB + cb][r];
        if (OUTMODE == 0) {
          Cf[(size_t)gr * N + gc] = vv;
        } else {
          if (gc < 2048) Cb0[(size_t)gr * 2048 + gc] = f2bf(vv);
          else Cb1[(size_t)gr * 2048 + gc - 2048] = f2bf(vv);
        }
      }
}

// ------- headwise: conv + swish, packed qkv proj, coalesced folded gates -------
__global__ __launch_bounds__(256) void headwise_kernel(
    const unsigned short* __restrict__ xm,
    const unsigned short* __restrict__ Wpk, const unsigned short* __restrict__ CgT,
    const float* __restrict__ cw, const float* __restrict__ cbias,
    const float* __restrict__ big, const float* __restrict__ bfg,
    unsigned short* __restrict__ q, unsigned short* __restrict__ k,
    unsigned short* __restrict__ v,
    float* __restrict__ igpre, float* __restrict__ fgpre) {
  __shared__ float red2[4][8];
  const int bs = blockIdx.x, t = threadIdx.x;
  const int s = bs & (S_LEN - 1);
  const int c0 = t * 8;
  float xa8[8], xm8[8];
  {
    float accv[8];
    const float4 cb0 = *(const float4*)(cbias + c0);
    const float4 cb1 = *(const float4*)(cbias + c0 + 4);
    accv[0] = cb0.x; accv[1] = cb0.y; accv[2] = cb0.z; accv[3] = cb0.w;
    accv[4] = cb1.x; accv[5] = cb1.y; accv[6] = cb1.z; accv[7] = cb1.w;
#pragma unroll
    for (int i = 0; i < 4; ++i) {
      if (s - 3 + i >= 0) {
        const short8v xv = *(const short8v*)(xm + (size_t)(bs - 3 + i) * INNERD + c0);
        const float4 w0 = *(const float4*)(cw + i * INNERD + c0);
        const float4 w1 = *(const float4*)(cw + i * INNERD + c0 + 4);
        const float wv2[8] = {w0.x, w0.y, w0.z, w0.w, w1.x, w1.y, w1.z, w1.w};
#pragma unroll
        for (int u = 0; u < 8; ++u) accv[u] += bf2f((unsigned short)xv[u]) * wv2[u];
      }
    }
    const short8v xs = *(const short8v*)(xm + (size_t)bs * INNERD + c0);
#pragma unroll
    for (int u = 0; u < 8; ++u) { xm8[u] = bf2f((unsigned short)xs[u]); xa8[u] = swishf(accv[u]); }
  }
  short8v qo, ko, vo;
#pragma unroll
  for (int hh = 0; hh < 2; ++hh)
#pragma unroll
    for (int sub = 0; sub < 2; ++sub) {
      const short8v wq = *(const short8v*)(Wpk + ((size_t)(0 + hh * 2 + sub) * 256 + t) * 8);
      const short8v wk = *(const short8v*)(Wpk + ((size_t)(4 + hh * 2 + sub) * 256 + t) * 8);
      const short8v wv3 = *(const short8v*)(Wpk + ((size_t)(8 + hh * 2 + sub) * 256 + t) * 8);
      float ql = 0, qh = 0, kl = 0, kh2 = 0, vl = 0, vh = 0;
#pragma unroll
      for (int d = 0; d < 4; ++d) {
        const float xa = xa8[hh * 4 + d], xv2 = xm8[hh * 4 + d];
        ql += bf2f((unsigned short)wq[d]) * xa;
        qh += bf2f((unsigned short)wq[4 + d]) * xa;
        kl += bf2f((unsigned short)wk[d]) * xa;
        kh2 += bf2f((unsigned short)wk[4 + d]) * xa;
        vl += bf2f((unsigned short)wv3[d]) * xv2;
        vh += bf2f((unsigned short)wv3[4 + d]) * xv2;
      }
      qo[hh * 4 + sub * 2] = (short)f2bf(ql); qo[hh * 4 + sub * 2 + 1] = (short)f2bf(qh);
      ko[hh * 4 + sub * 2] = (short)f2bf(kl); ko[hh * 4 + sub * 2 + 1] = (short)f2bf(kh2);
      vo[hh * 4 + sub * 2] = (short)f2bf(vl); vo[hh * 4 + sub * 2 + 1] = (short)f2bf(vh);
    }
  *(short8v*)(q + (size_t)bs * INNERD + c0) = qo;
  *(short8v*)(k + (size_t)bs * INNERD + c0) = ko;
  *(short8v*)(v + (size_t)bs * INNERD + c0) = vo;
  float r8[8];
#pragma unroll
  for (int j = 0; j < 4; ++j) {
    const short8v ca = *(const short8v*)(CgT + (size_t)j * INNERD + c0);
    const short8v cm = *(const short8v*)(CgT + (size_t)(4 + j) * INNERD + c0);
    const short8v fa = *(const short8v*)(CgT + (size_t)(8 + j) * INNERD + c0);
    const short8v fm = *(const short8v*)(CgT + (size_t)(12 + j) * INNERD + c0);
    float si = 0.f, sf = 0.f;
#pragma unroll
    for (int u = 0; u < 8; ++u) {
      si += xa8[u] * bf2f((unsigned short)ca[u]) + xm8[u] * bf2f((unsigned short)cm[u]);
      sf += xa8[u] * bf2f((unsigned short)fa[u]) + xm8[u] * bf2f((unsigned short)fm[u]);
    }
    r8[j] = si; r8[4 + j] = sf;
  }
  const int l = t & 63;
  const bool b1 = (l & 1), b2 = (l & 2), b4 = (l & 4);
  float t4[4];
#pragma unroll
  for (int i = 0; i < 4; ++i) {
    const float send = b1 ? r8[i] : r8[i + 4];
    const float recv = __shfl_xor(send, 1, 64);
    t4[i] = (b1 ? r8[i + 4] : r8[i]) + recv;
  }
  float u2[2];
#pragma unroll
  for (int i = 0; i < 2; ++i) {
    const float send = b2 ? t4[i] : t4[i + 2];
    const float recv = __shfl_xor(send, 2, 64);
    u2[i] = (b2 ? t4[i + 2] : t4[i]) + recv;
  }
  float wsum;
  {
    const float send = b4 ? u2[0] : u2[1];
    const float recv = __shfl_xor(send, 4, 64);
    wsum = (b4 ? u2[1] : u2[0]) + recv;
  }
  wsum += __shfl_xor(wsum, 8, 64);
  wsum += __shfl_xor(wsum, 16, 64);
  wsum += __shfl_xor(wsum, 32, 64);
  if (l < 8) {
    const int perm = ((l & 1) << 2) | (l & 2) | ((l >> 2) & 1);
    red2[t >> 6][perm] = wsum;
  }
  __syncthreads();
  if (t < 8) {
    const float sum = red2[0][t] + red2[1][t] + red2[2][t] + red2[3][t];
    const int b = bs >> 11;
    if (t < 4) igpre[((size_t)(b * NHEAD + t)) * S_LEN + s] = sum + big[t];
    else fgpre[((size_t)(b * NHEAD + t - 4)) * S_LEN + s] = sum + bfg[t - 4];
  }
}

// -------- per-(b,n) scan --------
__global__ __launch_bounds__(256) void scan_kernel(const float* __restrict__ igpre,
                                                   const float* __restrict__ fgpre,
                                                   float* __restrict__ a_o,
                                                   float* __restrict__ rm_o,
                                                   float* __restrict__ e_o) {
  __shared__ float sd[256];
  const int bn = blockIdx.x, t = threadIdx.x;
  const size_t base = (size_t)bn * S_LEN + t * 8;
  float cs[8];
  float run = 0.0f;
#pragma unroll
  for (int u = 0; u < 8; ++u) { run += logsigf(fgpre[base + u]); cs[u] = run; }
  sd[t] = run;
  __syncthreads();
  for (int off = 1; off < 256; off <<= 1) {
    const float vv2 = (t >= off) ? sd[t - off] : 0.0f;
    __syncthreads();
    sd[t] += vv2;
    __syncthreads();
  }
  const float exs = (t > 0) ? sd[t - 1] : 0.0f;
  __syncthreads();
  float av[8], pm[8];
  float rmax = -INFINITY;
#pragma unroll
  for (int u = 0; u < 8; ++u) {
    const float L = exs + cs[u];
    cs[u] = L;
    av[u] = igpre[base + u] - L;
    rmax = fmaxf(rmax, av[u]);
    pm[u] = rmax;
  }
  sd[t] = rmax;
  __syncthreads();
  for (int off = 1; off < 256; off <<= 1) {
    const float vv2 = (t >= off) ? sd[t - off] : -INFINITY;
    __syncthreads();
    sd[t] = fmaxf(sd[t], vv2);
    __syncthreads();
  }
  const float exm = (t > 0) ? sd[t - 1] : -INFINITY;
#pragma unroll
  for (int u = 0; u < 8; ++u) {
    const float rmv = fmaxf(exm, pm[u]);
    a_o[base + u] = av[u];
    rm_o[base + u] = rmv;
    e_o[base + u] = expf(-(cs[u] + rmv));
  }
}

// ----- mLSTM core: direct-global K fragments (no K LDS), double-buffered P, 1 barrier/tile -----
__global__ __launch_bounds__(512, 2) void mlstm_mfma(
    const unsigned short* __restrict__ qg, const unsigned short* __restrict__ kg,
    const unsigned short* __restrict__ vtg,
    const float* __restrict__ ag, const float* __restrict__ rmg,
    float* __restrict__ hraw, float* __restrict__ rsumg) {
  __shared__ unsigned short Ps[2][64 * 64];  // 2 x 8KB, rows 128B, XOR (row&7)<<4
  __shared__ float rsl[8][16];
  const int tid = threadIdx.x;
  const int w = tid >> 6, l = tid & 63;
  const int lm = l & 15, l4 = l >> 4;
  const int beta = blockIdx.x;
  const int bn = beta & 7;          // XCD locality for K/vT panels
  const int part = (beta >> 3) & 1;
  const int idx = beta >> 4;
  const int qi = (idx < 16) ? (31 - idx) : (idx - 16);  // heavy blocks first, pair-balanced
  const int i0 = qi << 6;
  const int b = bn >> 2, n = bn & 3;
  float* hp = hraw + (size_t)part * ((size_t)BATCH * S_LEN * INNERD);
  float* rp = rsumg + (size_t)part * ((size_t)BATCH * NHEAD * S_LEN);

  const int rA = ((w >> 1) << 4) + lm;
  short8v qf[16];
  {
    const unsigned short* qp = qg + (size_t)(b * S_LEN + i0 + rA) * INNERD + n * DHEAD + l4 * 8;
#pragma unroll
    for (int ks = 0; ks < 16; ++ks) qf[ks] = *(const short8v*)(qp + ks * 32);
  }
  const int rD = ((w >> 1) << 4) + (l4 << 2);
  float rm4[4];
#pragma unroll
  for (int r = 0; r < 4; ++r) rm4[r] = rmg[(size_t)bn * S_LEN + i0 + rD + r];
  const int cb0 = (w & 1) << 1;

  // per-lane K fragment bases (B-frag for QK loads straight from K's [s][d] layout)
  const unsigned short* kb0 = kg + (size_t)(b * S_LEN + cb0 * 16 + lm) * INNERD + n * DHEAD + l4 * 8;
  const unsigned short* kb1 = kb0 + (size_t)16 * INNERD;

  f32x4 acc[16];
#pragma unroll
  for (int i2 = 0; i2 < 16; ++i2) acc[i2] = (f32x4){0.f, 0.f, 0.f, 0.f};
  float rs4[4] = {0.f, 0.f, 0.f, 0.f};

  const int ntau = (qi + 2 - part) >> 1;  // tiles jt = part + 2*tau
  for (int tau = 0; tau < ntau; ++tau) {
    const int j0 = (part + 2 * tau) << 6;
    const int cur = tau & 1;
    // V B-fragments direct from L2 (vT layout: contiguous in j)
    short8v vf[8];
#pragma unroll
    for (int db = 0; db < 4; ++db)
#pragma unroll
      for (int ks = 0; ks < 2; ++ks)
        vf[db * 2 + ks] = *(const short8v*)(vtg + (size_t)(bn * DHEAD + w * 64 + db * 16 + lm) * S_LEN + j0 + ks * 32 + l4 * 8);
    const float a0 = ag[(size_t)bn * S_LEN + j0 + cb0 * 16 + lm];
    const float a1 = ag[(size_t)bn * S_LEN + j0 + cb0 * 16 + 16 + lm];
    // --- QK^T: K frags direct from global (L1/L2-cached) ---
    const unsigned short* kp0 = kb0 + (size_t)j0 * INNERD;
    const unsigned short* kp1 = kb1 + (size_t)j0 * INNERD;
    f32x4 s0 = (f32x4){0.f, 0.f, 0.f, 0.f}, s1 = (f32x4){0.f, 0.f, 0.f, 0.f};
#pragma unroll
    for (int ks = 0; ks < 16; ++ks) {
      const short8v k0 = *(const short8v*)(kp0 + ks * 32);
      const short8v k1 = *(const short8v*)(kp1 + ks * 32);
      s0 = MFMA_BF16(qf[ks], k0, s0);
      s1 = MFMA_BF16(qf[ks], k1, s1);
    }
    // --- gate + causal mask + rowsum + P write (buffer cur) ---
#pragma unroll
    for (int half = 0; half < 2; ++half) {
      const f32x4 sv = half ? s1 : s0;
      const float av = half ? a1 : a0;
      const int jl = (cb0 + half) * 16 + lm;
#pragma unroll
      for (int r = 0; r < 4; ++r) {
        const int il = rD + r;
        const float es = __expf(av - rm4[r]);
        const float p = (j0 + jl <= i0 + il) ? sv[r] * SCALE_QK * es : 0.0f;
        rs4[r] += p;
        *((unsigned short*)((char*)Ps[cur] + il * 128 + ((jl * 2) ^ ((il & 7) << 4)))) = f2bf(p);
      }
    }
    asm volatile("s_waitcnt lgkmcnt(0)" ::: "memory");
    __builtin_amdgcn_sched_barrier(0);
    __builtin_amdgcn_s_barrier();
    // --- PV (reads buffer cur; next tile writes cur^1, so no trailing barrier needed) ---
#pragma unroll
    for (int ks = 0; ks < 2; ++ks) {
      short8v pa[4];
#pragma unroll
      for (int rb = 0; rb < 4; ++rb)
        pa[rb] = *(const short8v*)((const char*)Ps[cur] + (rb * 16 + lm) * 128 + ((ks * 64 + l4 * 16) ^ ((lm & 7) << 4)));
      __builtin_amdgcn_s_setprio(1);
#pragma unroll
      for (int rb = 0; rb < 4; ++rb)
#pragma unroll
        for (int db = 0; db < 4; ++db)
          acc[rb * 4 + db] = MFMA_BF16(pa[rb], vf[db * 2 + ks], acc[rb * 4 + db]);
      __builtin_amdgcn_s_setprio(0);
    }
  }
  // rowsum combine via LDS (two waves share each 16-row block)
#pragma unroll
  for (int r = 0; r < 4; ++r) {
    float v2 = rs4[r];
    v2 += __shfl_xor(v2, 1, 64);
    v2 += __shfl_xor(v2, 2, 64);
    v2 += __shfl_xor(v2, 4, 64);
    v2 += __shfl_xor(v2, 8, 64);
    if (lm == 0) rsl[w][l4 * 4 + r] = v2;
  }
  asm volatile("s_waitcnt lgkmcnt(0)" ::: "memory");
  __builtin_amdgcn_s_barrier();
  if (tid < 64) {
    const int rblk = tid >> 4, rloc = tid & 15;
    rp[(size_t)bn * S_LEN + i0 + rblk * 16 + rloc] = rsl[rblk * 2][rloc] + rsl[rblk * 2 + 1][rloc];
  }
  // raw h partial store (zero when loop empty)
#pragma unroll
  for (int rb = 0; rb < 4; ++rb)
#pragma unroll
    for (int db = 0; db < 4; ++db) {
      float* dst = hp + (size_t)(b * S_LEN + i0 + rb * 16 + l4 * 4) * INNERD + n * DHEAD + w * 64 + db * 16 + lm;
#pragma unroll
      for (int r = 0; r < 4; ++r) dst[(size_t)r * INNERD] = acc[rb * 4 + db][r];
    }
}

// ------- mhln: merge partials + norm + LN + conv-skip + swish(z), bf16 out -------
__global__ __launch_bounds__(256) void mhln_kernel(
    const float* __restrict__ h, const unsigned short* __restrict__ xm,
    const unsigned short* __restrict__ zb,
    const float* __restrict__ cw, const float* __restrict__ cbias,
    const float* __restrict__ rsumg, const float* __restrict__ eg,
    const float* __restrict__ normw, const float* __restrict__ skip,
    unsigned short* __restrict__ hstate) {
  const int bs = blockIdx.x, t = threadIdx.x;
  const int bb = bs >> 11, s = bs & (S_LEN - 1);
  const int n = t >> 6, lane = t & 63;
  const int cp0 = n * DHEAD + lane * 8;
  const size_t hb = (size_t)bs * INNERD + cp0;
  const size_t HOFF = (size_t)BATCH * S_LEN * INNERD;
  const int bn = bb * NHEAD + n;
  const float rsv = rsumg[(size_t)bn * S_LEN + s] + rsumg[(size_t)BATCH * NHEAD * S_LEN + bn * S_LEN + s];
  const float ev = eg[(size_t)bn * S_LEN + s];
  const float inorm = 1.0f / (fmaxf(fabsf(rsv), ev) + 1e-6f);
  const float4 v0 = *(const float4*)(h + hb);
  const float4 v1 = *(const float4*)(h + hb + 4);
  const float4 u0 = *(const float4*)(h + HOFF + hb);
  const float4 u1 = *(const float4*)(h + HOFF + hb + 4);
  float vals[8] = {(v0.x + u0.x) * inorm, (v0.y + u0.y) * inorm, (v0.z + u0.z) * inorm,
                   (v0.w + u0.w) * inorm, (v1.x + u1.x) * inorm, (v1.y + u1.y) * inorm,
                   (v1.z + u1.z) * inorm, (v1.w + u1.w) * inorm};
  float sum = 0.0f;
#pragma unroll
  for (int u = 0; u < 8; ++u) sum += vals[u];
#pragma unroll
  for (int m = 32; m >= 1; m >>= 1) sum += __shfl_xor(sum, m, 64);
  const float mu = sum * (1.0f / 512.0f);
  float vs2 = 0.0f;
#pragma unroll
  for (int u = 0; u < 8; ++u) { const float d = vals[u] - mu; vs2 += d * d; }
#pragma unroll
  for (int m = 32; m >= 1; m >>= 1) vs2 += __shfl_xor(vs2, m, 64);
  const float rstd = rsqrtf(vs2 * (1.0f / 512.0f) + 1e-6f);
  float xa8[8];
  {
    float accv[8];
#pragma unroll
    for (int u = 0; u < 8; ++u) accv[u] = cbias[cp0 + u];
#pragma unroll
    for (int i2 = 0; i2 < 4; ++i2) {
      const int sj = s - 3 + i2;
      if (sj >= 0) {
        const short8v xv = *(const short8v*)(xm + (size_t)(bs - 3 + i2) * INNERD + cp0);
#pragma unroll
        for (int u = 0; u < 8; ++u)
          accv[u] += bf2f((unsigned short)xv[u]) * cw[i2 * INNERD + cp0 + u];
      }
    }
#pragma unroll
    for (int u = 0; u < 8; ++u) xa8[u] = swishf(accv[u]);
  }
  const short8v zv = *(const short8v*)(zb + (size_t)bs * INNERD + cp0);
  short8v o;
#pragma unroll
  for (int u = 0; u < 8; ++u) {
    const int cp = cp0 + u;
    const float hn = (vals[u] - mu) * rstd * normw[cp];
    const float z = bf2f((unsigned short)zv[u]);
    o[u] = (short)f2bf((hn + skip[cp] * xa8[u]) * swishf(z));
  }
  *(short8v*)(hstate + hb) = o;
}

extern "C" void kernel_launch(void* const* d_in, const int* in_sizes, int n_in,
                              void* d_out, int out_size, void* d_ws, size_t ws_size,
                              hipStream_t stream) {
  const float* x     = (const float*)d_in[0];
  const float* Wup   = (const float*)d_in[1];
  const float* cw    = (const float*)d_in[2];
  const float* cb    = (const float*)d_in[3];
  const float* Wq    = (const float*)d_in[4];
  const float* Wk    = (const float*)d_in[5];
  const float* Wv    = (const float*)d_in[6];
  const float* Wig   = (const float*)d_in[7];
  const float* big   = (const float*)d_in[8];
  const float* Wfg   = (const float*)d_in[9];
  const float* bfg   = (const float*)d_in[10];
  const float* normw = (const float*)d_in[11];
  const float* skip  = (const float*)d_in[12];
  const float* Wdown = (const float*)d_in[13];
  float* out = (float*)d_out;

  float* ws = (float*)d_ws;
  size_t off = 0;
  const size_t MR = (size_t)BATCH * S_LEN;  // 4096
  const size_t GSZ = (size_t)BATCH * NHEAD * S_LEN;  // 16384
  unsigned short* xm  = (unsigned short*)(ws + off); off += MR * INNERD / 2;
  unsigned short* zb  = (unsigned short*)(ws + off); off += MR * INNERD / 2;
  float* hraw         = ws + off;                    off += 2 * MR * INNERD;   // two partials
  unsigned short* qb  = (unsigned short*)(ws + off); off += MR * INNERD / 2;
  unsigned short* kb  = (unsigned short*)(ws + off); off += MR * INNERD / 2;
  unsigned short* vt  = (unsigned short*)(ws + off); off += MR * INNERD / 2;
  float* igpre  = ws + off; off += GSZ;
  float* fgpre  = ws + off; off += GSZ;
  float* a_buf  = ws + off; off += GSZ;
  float* rm_buf = ws + off; off += GSZ;
  float* e_buf  = ws + off; off += GSZ;
  float* rsum   = ws + off; off += 2 * GSZ;          // two partials
  unsigned short* Wpk = (unsigned short*)(ws + off); off += 12 * 256 * 8 / 2;
  unsigned short* CgT = (unsigned short*)(ws + off); off += 16 * (size_t)INNERD / 2;
  if (ws_size < off * sizeof(float)) return;

  // aliases into dead regions
  unsigned short* vb     = (unsigned short*)hraw;                       // dead before mlstm writes
  unsigned short* x_bf   = (unsigned short*)(hraw + MR * INNERD);       // part-1 region, dead before mlstm
  unsigned short* WupT   = vt;                                          // dead before trv writes vt
  unsigned short* WdT    = kb;                                          // dead after mlstm
  unsigned short* hstate = qb;                                          // dead after mlstm

  prep_kernel<<<1, 256, 0, stream>>>(Wq, Wk, Wv, Wig, Wfg, Wpk, CgT);
  cast_kernel<<<2048, 256, 0, stream>>>(x, x_bf);
  trc_kernel<<<dim3(32, 8), 256, 0, stream>>>(Wup, WupT, 1024, 4096);
  gemm_bf16<128, 1><<<dim3(32, 32), 256, 0, stream>>>(x_bf, WupT, nullptr, xm, zb, 4096, 4096, 1024);
  headwise_kernel<<<4096, 256, 0, stream>>>(xm, Wpk, CgT, cw, cb, big, bfg,
                                            qb, kb, vb, igpre, fgpre);
  trv_kernel<<<dim3(16, 4, 8), 256, 0, stream>>>(vb, vt);
  scan_kernel<<<8, 256, 0, stream>>>(igpre, fgpre, a_buf, rm_buf, e_buf);
  mlstm_mfma<<<512, 512, 0, stream>>>(qb, kb, vt, a_buf, rm_buf, hraw, rsum);
  trc_kernel<<<dim3(8, 16), 256, 0, stream>>>(Wdown, WdT, 2048, 1024);
  mhln_kernel<<<4096, 256, 0, stream>>>(hraw, xm, zb, cw, cb, rsum, e_buf, normw, skip, hstate);
  gemm_bf16<64, 0><<<dim3(16, 32), 256, 0, stream>>>(hstate, WdT, out, nullptr, nullptr, 4096, 1024, 2048);
}

// Round 7
// 382.130 us; speedup vs baseline: 1.3745x; 1.3745x over previous
//
#include <hip/hip_runtime.h>
#include <math.h>

#define S_LEN 2048
#define INNERD 2048
#define NHEAD 4
#define DHEAD 512
#define BATCH 2
#define SCALE_QK 0.044194173824159216f

typedef __attribute__((ext_vector_type(8))) short short8v;
typedef __attribute__((ext_vector_type(4))) float f32x4;

#define MFMA_BF16(A, B, C) __builtin_amdgcn_mfma_f32_16x16x32_bf16(A, B, C, 0, 0, 0)

__device__ __forceinline__ void gll16(const void* g, void* l) {
  __builtin_amdgcn_global_load_lds((const __attribute__((address_space(1))) unsigned int*)g,
                                   (__attribute__((address_space(3))) unsigned int*)l,
                                   16, 0, 0);
}

__device__ __forceinline__ unsigned short f2bf(float x) {
  union { float f; unsigned u; } v; v.f = x;
  unsigned r = v.u + 0x7FFFu + ((v.u >> 16) & 1u);
  return (unsigned short)(r >> 16);
}
__device__ __forceinline__ float bf2f(unsigned short x) {
  union { unsigned u; float f; } v; v.u = ((unsigned)x) << 16; return v.f;
}
__device__ __forceinline__ float swishf(float x) { return x / (1.0f + __expf(-x)); }
__device__ __forceinline__ float logsigf(float x) {
  return (x >= 0.0f) ? -log1pf(expf(-x)) : (x - log1pf(expf(x)));
}

// ---------- trc body: f32 [R][C] -> bf16 [C][R], 128x128 tile ----------
__device__ __forceinline__ void trc_body(const float* __restrict__ src,
                                         unsigned short* __restrict__ dst,
                                         int R, int C, int r0, int c0, int t) {
  const int rb = (t >> 4) * 8, cb2 = (t & 15) * 8;
  float vreg[8][8];
#pragma unroll
  for (int u = 0; u < 8; ++u) {
    const float4 p0 = *(const float4*)(src + (size_t)(r0 + rb + u) * C + c0 + cb2);
    const float4 p1 = *(const float4*)(src + (size_t)(r0 + rb + u) * C + c0 + cb2 + 4);
    vreg[u][0] = p0.x; vreg[u][1] = p0.y; vreg[u][2] = p0.z; vreg[u][3] = p0.w;
    vreg[u][4] = p1.x; vreg[u][5] = p1.y; vreg[u][6] = p1.z; vreg[u][7] = p1.w;
  }
#pragma unroll
  for (int j = 0; j < 8; ++j) {
    short8v o;
#pragma unroll
    for (int u = 0; u < 8; ++u) o[u] = (short)f2bf(vreg[u][j]);
    *(short8v*)(dst + (size_t)(c0 + cb2 + j) * R + r0 + rb) = o;
  }
}

// ---- setup: cast x (blocks 0..2047) + trc Wup (2048..2303) + trc Wdown (2304..2431)
//      + prep weights (2432) ----
__global__ __launch_bounds__(256) void setup_kernel(
    const float* __restrict__ x, const float* __restrict__ Wup,
    const float* __restrict__ Wdown,
    const float* __restrict__ Wq, const float* __restrict__ Wk, const float* __restrict__ Wv,
    const float* __restrict__ Wig, const float* __restrict__ Wfg,
    unsigned short* __restrict__ x_bf, unsigned short* __restrict__ WupT,
    unsigned short* __restrict__ WdT,
    unsigned short* __restrict__ Wpk, unsigned short* __restrict__ CgT) {
  const int bid = blockIdx.x;
  const int t = threadIdx.x;
  if (bid < 2048) {
    const int i = (bid * 256 + t) * 8;
    const float4 a = *(const float4*)(x + i);
    const float4 b = *(const float4*)(x + i + 4);
    short8v o;
    o[0] = (short)f2bf(a.x); o[1] = (short)f2bf(a.y); o[2] = (short)f2bf(a.z); o[3] = (short)f2bf(a.w);
    o[4] = (short)f2bf(b.x); o[5] = (short)f2bf(b.y); o[6] = (short)f2bf(b.z); o[7] = (short)f2bf(b.w);
    *(short8v*)(x_bf + i) = o;
  } else if (bid < 2304) {
    const int local = bid - 2048;
    trc_body(Wup, WupT, 1024, 4096, (local >> 5) * 128, (local & 31) * 128, t);
  } else if (bid < 2432) {
    const int local = bid - 2304;
    trc_body(Wdown, WdT, 2048, 1024, (local >> 3) * 128, (local & 7) * 128, t);
  } else {
    // prep: pack qkv weights + fold gate weights
    float wq[2][16], wk[2][16], wv[2][16];
#pragma unroll
    for (int hh = 0; hh < 2; ++hh) {
      const int h = 2 * t + hh;
#pragma unroll
      for (int j = 0; j < 16; ++j) {
        wq[hh][j] = Wq[(size_t)h * 16 + j];
        wk[hh][j] = Wk[(size_t)h * 16 + j];
        wv[hh][j] = Wv[(size_t)h * 16 + j];
      }
    }
#pragma unroll
    for (int hh = 0; hh < 2; ++hh)
#pragma unroll
      for (int sub = 0; sub < 2; ++sub) {
        short8v oq, ok, ov;
#pragma unroll
        for (int j = 0; j < 8; ++j) {
          oq[j] = (short)f2bf(wq[hh][sub * 8 + j]);
          ok[j] = (short)f2bf(wk[hh][sub * 8 + j]);
          ov[j] = (short)f2bf(wv[hh][sub * 8 + j]);
        }
        *(short8v*)(Wpk + ((size_t)(0 + hh * 2 + sub) * 256 + t) * 8) = oq;
        *(short8v*)(Wpk + ((size_t)(4 + hh * 2 + sub) * 256 + t) * 8) = ok;
        *(short8v*)(Wpk + ((size_t)(8 + hh * 2 + sub) * 256 + t) * 8) = ov;
      }
#pragma unroll
    for (int u = 0; u < 8; ++u) {
      const int hh = u >> 2, d = u & 3;
      const int h = 2 * t + hh;
      float cia[4] = {0, 0, 0, 0}, cim[4] = {0, 0, 0, 0};
      float cfa[4] = {0, 0, 0, 0}, cfm[4] = {0, 0, 0, 0};
#pragma unroll
      for (int o = 0; o < 4; ++o) {
        const int row = h * 4 + o;
        const float aq = wq[hh][o * 4 + d], ak = wk[hh][o * 4 + d], av = wv[hh][o * 4 + d];
#pragma unroll
        for (int g = 0; g < 4; ++g) {
          cia[g] += aq * Wig[(size_t)row * 4 + g] + ak * Wig[(size_t)(INNERD + row) * 4 + g];
          cim[g] += av * Wig[(size_t)(2 * INNERD + row) * 4 + g];
          cfa[g] += aq * Wfg[(size_t)row * 4 + g] + ak * Wfg[(size_t)(INNERD + row) * 4 + g];
          cfm[g] += av * Wfg[(size_t)(2 * INNERD + row) * 4 + g];
        }
      }
      const int c = t * 8 + u;
#pragma unroll
      for (int g = 0; g < 4; ++g) {
        CgT[(size_t)(g) * INNERD + c] = f2bf(cia[g]);
        CgT[(size_t)(4 + g) * INNERD + c] = f2bf(cim[g]);
        CgT[(size_t)(8 + g) * INNERD + c] = f2bf(cfa[g]);
        CgT[(size_t)(12 + g) * INNERD + c] = f2bf(cfm[g]);
      }
    }
  }
}

// ------------- v bf16 [4096][2048] -> vT bf16 [8][512][2048] -------------
__global__ __launch_bounds__(256) void trv_kernel(const unsigned short* __restrict__ v,
                                                  unsigned short* __restrict__ vt) {
  const int t = threadIdx.x;
  const int s0 = blockIdx.x * 128;
  const int d0 = blockIdx.y * 128;
  const int bn = blockIdx.z;
  const int b = bn >> 2, n = bn & 3;
  const int sb = (t >> 4) * 8, db = (t & 15) * 8;
  unsigned short r[8][8];
#pragma unroll
  for (int u = 0; u < 8; ++u) {
    const short8v x2 = *(const short8v*)(v + (size_t)(b * S_LEN + s0 + sb + u) * INNERD + n * DHEAD + d0 + db);
#pragma unroll
    for (int j = 0; j < 8; ++j) r[u][j] = (unsigned short)x2[j];
  }
#pragma unroll
  for (int j = 0; j < 8; ++j) {
    short8v o;
#pragma unroll
    for (int u = 0; u < 8; ++u) o[u] = (short)r[u][j];
    *(short8v*)(vt + (size_t)(bn * DHEAD + d0 + db + j) * S_LEN + s0 + sb) = o;
  }
}

// ---------------- bf16 MFMA GEMM: C[M,N] = A[M,K] * Bt[N,K]^T, tile 128xBN ----------------
template <int BN, int OUTMODE>
__global__ __launch_bounds__(256) void gemm_bf16(const unsigned short* __restrict__ A,
                                                 const unsigned short* __restrict__ Bt,
                                                 float* __restrict__ Cf,
                                                 unsigned short* __restrict__ Cb0,
                                                 unsigned short* __restrict__ Cb1,
                                                 int M, int N, int K) {
  constexpr int CB = BN / 32;
  __shared__ unsigned short As[128 * 64];
  __shared__ unsigned short Bs[BN * 64];
  const int tid = threadIdx.x;
  const int w = tid >> 6, l = tid & 63;
  const int lm = l & 15, l4 = l >> 4, l8 = l & 7, lr = l >> 3;
  const int nwg = gridDim.x * gridDim.y;
  int bid = blockIdx.y * gridDim.x + blockIdx.x;
  const int cpx = nwg >> 3;
  bid = (bid & 7) * cpx + (bid >> 3);  // XCD swizzle (nwg % 8 == 0)
  const int bx = bid % gridDim.x, by = bid / gridDim.x;
  const int row0 = by * 128, col0 = bx * BN;
  const int wm = w >> 1, wn = w & 1;
  f32x4 acc[4 * CB];
#pragma unroll
  for (int i2 = 0; i2 < 4 * CB; ++i2) acc[i2] = (f32x4){0.f, 0.f, 0.f, 0.f};

  const int scol = (l8 * 16) ^ (lr << 4);

  for (int k0 = 0; k0 < K; k0 += 64) {
#pragma unroll
    for (int it = 0; it < 4; ++it) {
      const int r = it * 32 + w * 8 + lr;
      gll16((const char*)A + ((size_t)(row0 + r) * K + k0) * 2 + scol,
            (char*)As + (size_t)(it * 32 + w * 8) * 128);
    }
#pragma unroll
    for (int it = 0; it < BN / 32; ++it) {
      const int r = it * 32 + w * 8 + lr;
      gll16((const char*)Bt + ((size_t)(col0 + r) * K + k0) * 2 + scol,
            (char*)Bs + (size_t)(it * 32 + w * 8) * 128);
    }
    __syncthreads();
#pragma unroll
    for (int ks = 0; ks < 2; ++ks) {
      short8v af[4], bfr[CB];
#pragma unroll
      for (int rb = 0; rb < 4; ++rb) {
        const int row = wm * 64 + rb * 16 + lm;
        af[rb] = *(const short8v*)((const char*)As + row * 128 + ((ks * 64 + l4 * 16) ^ ((lm & 7) << 4)));
      }
#pragma unroll
      for (int cb = 0; cb < CB; ++cb) {
        const int row = wn * (BN / 2) + cb * 16 + lm;
        bfr[cb] = *(const short8v*)((const char*)Bs + row * 128 + ((ks * 64 + l4 * 16) ^ ((lm & 7) << 4)));
      }
#pragma unroll
      for (int rb = 0; rb < 4; ++rb)
#pragma unroll
        for (int cb = 0; cb < CB; ++cb)
          acc[rb * CB + cb] = MFMA_BF16(af[rb], bfr[cb], acc[rb * CB + cb]);
    }
    __syncthreads();
  }
#pragma unroll
  for (int rb = 0; rb < 4; ++rb)
#pragma unroll
    for (int cb = 0; cb < CB; ++cb)
#pragma unroll
      for (int r = 0; r < 4; ++r) {
        const int gr = row0 + wm * 64 + rb * 16 + l4 * 4 + r;
        const int gc = col0 + wn * (BN / 2) + cb * 16 + lm;
        const float vv = acc[rb * CB + cb][r];
        if (OUTMODE == 0) {
          Cf[(size_t)gr * N + gc] = vv;
        } else {
          if (gc < 2048) Cb0[(size_t)gr * 2048 + gc] = f2bf(vv);
          else Cb1[(size_t)gr * 2048 + gc - 2048] = f2bf(vv);
        }
      }
}

// ------- headwise: conv + swish, packed qkv proj, coalesced folded gates -------
__global__ __launch_bounds__(256) void headwise_kernel(
    const unsigned short* __restrict__ xm,
    const unsigned short* __restrict__ Wpk, const unsigned short* __restrict__ CgT,
    const float* __restrict__ cw, const float* __restrict__ cbias,
    const float* __restrict__ big, const float* __restrict__ bfg,
    unsigned short* __restrict__ q, unsigned short* __restrict__ k,
    unsigned short* __restrict__ v,
    float* __restrict__ igpre, float* __restrict__ fgpre) {
  __shared__ float red2[4][8];
  const int bs = blockIdx.x, t = threadIdx.x;
  const int s = bs & (S_LEN - 1);
  const int c0 = t * 8;
  float xa8[8], xm8[8];
  {
    float accv[8];
    const float4 cb0 = *(const float4*)(cbias + c0);
    const float4 cb1 = *(const float4*)(cbias + c0 + 4);
    accv[0] = cb0.x; accv[1] = cb0.y; accv[2] = cb0.z; accv[3] = cb0.w;
    accv[4] = cb1.x; accv[5] = cb1.y; accv[6] = cb1.z; accv[7] = cb1.w;
#pragma unroll
    for (int i = 0; i < 4; ++i) {
      if (s - 3 + i >= 0) {
        const short8v xv = *(const short8v*)(xm + (size_t)(bs - 3 + i) * INNERD + c0);
        const float4 w0 = *(const float4*)(cw + i * INNERD + c0);
        const float4 w1 = *(const float4*)(cw + i * INNERD + c0 + 4);
        const float wv2[8] = {w0.x, w0.y, w0.z, w0.w, w1.x, w1.y, w1.z, w1.w};
#pragma unroll
        for (int u = 0; u < 8; ++u) accv[u] += bf2f((unsigned short)xv[u]) * wv2[u];
      }
    }
    const short8v xs = *(const short8v*)(xm + (size_t)bs * INNERD + c0);
#pragma unroll
    for (int u = 0; u < 8; ++u) { xm8[u] = bf2f((unsigned short)xs[u]); xa8[u] = swishf(accv[u]); }
  }
  short8v qo, ko, vo;
#pragma unroll
  for (int hh = 0; hh < 2; ++hh)
#pragma unroll
    for (int sub = 0; sub < 2; ++sub) {
      const short8v wq = *(const short8v*)(Wpk + ((size_t)(0 + hh * 2 + sub) * 256 + t) * 8);
      const short8v wk = *(const short8v*)(Wpk + ((size_t)(4 + hh * 2 + sub) * 256 + t) * 8);
      const short8v wv3 = *(const short8v*)(Wpk + ((size_t)(8 + hh * 2 + sub) * 256 + t) * 8);
      float ql = 0, qh = 0, kl = 0, kh2 = 0, vl = 0, vh = 0;
#pragma unroll
      for (int d = 0; d < 4; ++d) {
        const float xa = xa8[hh * 4 + d], xv2 = xm8[hh * 4 + d];
        ql += bf2f((unsigned short)wq[d]) * xa;
        qh += bf2f((unsigned short)wq[4 + d]) * xa;
        kl += bf2f((unsigned short)wk[d]) * xa;
        kh2 += bf2f((unsigned short)wk[4 + d]) * xa;
        vl += bf2f((unsigned short)wv3[d]) * xv2;
        vh += bf2f((unsigned short)wv3[4 + d]) * xv2;
      }
      qo[hh * 4 + sub * 2] = (short)f2bf(ql); qo[hh * 4 + sub * 2 + 1] = (short)f2bf(qh);
      ko[hh * 4 + sub * 2] = (short)f2bf(kl); ko[hh * 4 + sub * 2 + 1] = (short)f2bf(kh2);
      vo[hh * 4 + sub * 2] = (short)f2bf(vl); vo[hh * 4 + sub * 2 + 1] = (short)f2bf(vh);
    }
  *(short8v*)(q + (size_t)bs * INNERD + c0) = qo;
  *(short8v*)(k + (size_t)bs * INNERD + c0) = ko;
  *(short8v*)(v + (size_t)bs * INNERD + c0) = vo;
  float r8[8];
#pragma unroll
  for (int j = 0; j < 4; ++j) {
    const short8v ca = *(const short8v*)(CgT + (size_t)j * INNERD + c0);
    const short8v cm = *(const short8v*)(CgT + (size_t)(4 + j) * INNERD + c0);
    const short8v fa = *(const short8v*)(CgT + (size_t)(8 + j) * INNERD + c0);
    const short8v fm = *(const short8v*)(CgT + (size_t)(12 + j) * INNERD + c0);
    float si = 0.f, sf = 0.f;
#pragma unroll
    for (int u = 0; u < 8; ++u) {
      si += xa8[u] * bf2f((unsigned short)ca[u]) + xm8[u] * bf2f((unsigned short)cm[u]);
      sf += xa8[u] * bf2f((unsigned short)fa[u]) + xm8[u] * bf2f((unsigned short)fm[u]);
    }
    r8[j] = si; r8[4 + j] = sf;
  }
  const int l = t & 63;
  const bool b1 = (l & 1), b2 = (l & 2), b4 = (l & 4);
  float t4[4];
#pragma unroll
  for (int i = 0; i < 4; ++i) {
    const float send = b1 ? r8[i] : r8[i + 4];
    const float recv = __shfl_xor(send, 1, 64);
    t4[i] = (b1 ? r8[i + 4] : r8[i]) + recv;
  }
  float u2[2];
#pragma unroll
  for (int i = 0; i < 2; ++i) {
    const float send = b2 ? t4[i] : t4[i + 2];
    const float recv = __shfl_xor(send, 2, 64);
    u2[i] = (b2 ? t4[i + 2] : t4[i]) + recv;
  }
  float wsum;
  {
    const float send = b4 ? u2[0] : u2[1];
    const float recv = __shfl_xor(send, 4, 64);
    wsum = (b4 ? u2[1] : u2[0]) + recv;
  }
  wsum += __shfl_xor(wsum, 8, 64);
  wsum += __shfl_xor(wsum, 16, 64);
  wsum += __shfl_xor(wsum, 32, 64);
  if (l < 8) {
    const int perm = ((l & 1) << 2) | (l & 2) | ((l >> 2) & 1);
    red2[t >> 6][perm] = wsum;
  }
  __syncthreads();
  if (t < 8) {
    const float sum = red2[0][t] + red2[1][t] + red2[2][t] + red2[3][t];
    const int b = bs >> 11;
    if (t < 4) igpre[((size_t)(b * NHEAD + t)) * S_LEN + s] = sum + big[t];
    else fgpre[((size_t)(b * NHEAD + t - 4)) * S_LEN + s] = sum + bfg[t - 4];
  }
}

// -------- per-(b,n) scan --------
__global__ __launch_bounds__(256) void scan_kernel(const float* __restrict__ igpre,
                                                   const float* __restrict__ fgpre,
                                                   float* __restrict__ a_o,
                                                   float* __restrict__ rm_o,
                                                   float* __restrict__ e_o) {
  __shared__ float sd[256];
  const int bn = blockIdx.x, t = threadIdx.x;
  const size_t base = (size_t)bn * S_LEN + t * 8;
  float cs[8];
  float run = 0.0f;
#pragma unroll
  for (int u = 0; u < 8; ++u) { run += logsigf(fgpre[base + u]); cs[u] = run; }
  sd[t] = run;
  __syncthreads();
  for (int off = 1; off < 256; off <<= 1) {
    const float vv2 = (t >= off) ? sd[t - off] : 0.0f;
    __syncthreads();
    sd[t] += vv2;
    __syncthreads();
  }
  const float exs = (t > 0) ? sd[t - 1] : 0.0f;
  __syncthreads();
  float av[8], pm[8];
  float rmax = -INFINITY;
#pragma unroll
  for (int u = 0; u < 8; ++u) {
    const float L = exs + cs[u];
    cs[u] = L;
    av[u] = igpre[base + u] - L;
    rmax = fmaxf(rmax, av[u]);
    pm[u] = rmax;
  }
  sd[t] = rmax;
  __syncthreads();
  for (int off = 1; off < 256; off <<= 1) {
    const float vv2 = (t >= off) ? sd[t - off] : -INFINITY;
    __syncthreads();
    sd[t] = fmaxf(sd[t], vv2);
    __syncthreads();
  }
  const float exm = (t > 0) ? sd[t - 1] : -INFINITY;
#pragma unroll
  for (int u = 0; u < 8; ++u) {
    const float rmv = fmaxf(exm, pm[u]);
    a_o[base + u] = av[u];
    rm_o[base + u] = rmv;
    e_o[base + u] = expf(-(cs[u] + rmv));
  }
}

// ---------------- mLSTM core: MFMA flash-style, double-buffered K, counted vmcnt ----------
// (R4-proven structure; bf16 partial output)
__global__ __launch_bounds__(512, 2) void mlstm_mfma(
    const unsigned short* __restrict__ qg, const unsigned short* __restrict__ kg,
    const unsigned short* __restrict__ vtg,
    const float* __restrict__ ag, const float* __restrict__ rmg,
    unsigned short* __restrict__ hraw, float* __restrict__ rsumg) {
  __shared__ unsigned short Ks[2][64 * 512];  // 2 x 64KB, rows 1KB, XOR (row&7)<<4
  __shared__ unsigned short Ps[64 * 64];      // 8KB, rows 128B, XOR (row&7)<<4
  __shared__ float rsl[8][16];
  const int tid = threadIdx.x;
  const int w = tid >> 6, l = tid & 63;
  const int lm = l & 15, l4 = l >> 4;
  const int beta = blockIdx.x;
  const int bn = beta & 7;          // XCD locality for K/vT panels
  const int part = (beta >> 3) & 1;
  const int idx = beta >> 4;
  const int qi = (idx < 16) ? (31 - idx) : (idx - 16);  // heavy blocks first, pair-balanced
  const int i0 = qi << 6;
  const int b = bn >> 2, n = bn & 3;
  unsigned short* hp = hraw + (size_t)part * ((size_t)BATCH * S_LEN * INNERD);
  float* rp = rsumg + (size_t)part * ((size_t)BATCH * NHEAD * S_LEN);

  const int rA = ((w >> 1) << 4) + lm;
  short8v qf[16];
  {
    const unsigned short* qp = qg + (size_t)(b * S_LEN + i0 + rA) * INNERD + n * DHEAD + l4 * 8;
#pragma unroll
    for (int ks = 0; ks < 16; ++ks) qf[ks] = *(const short8v*)(qp + ks * 32);
  }
  const int rD = ((w >> 1) << 4) + (l4 << 2);
  float rm4[4];
#pragma unroll
  for (int r = 0; r < 4; ++r) rm4[r] = rmg[(size_t)bn * S_LEN + i0 + rD + r];
  const int cb0 = (w & 1) << 1;

  f32x4 acc[16];
#pragma unroll
  for (int i2 = 0; i2 < 16; ++i2) acc[i2] = (f32x4){0.f, 0.f, 0.f, 0.f};
  float rs4[4] = {0.f, 0.f, 0.f, 0.f};

  // tiles for this part: jt = part + 2*tau, tau in [0, ntau)
  const int ntau = (qi + 2 - part) >> 1;
  __builtin_amdgcn_sched_barrier(0);
  // prologue stage: tile 0 into Ks[0]  (8 gll16 per thread)
  if (ntau > 0) {
#pragma unroll
    for (int it = 0; it < 8; ++it) {
      const int row = it * 8 + w;
      gll16((const char*)kg + ((size_t)(b * S_LEN + part * 64 + row) * INNERD + n * DHEAD) * 2 + ((l * 16) ^ (w << 4)),
            (char*)Ks[0] + row * 1024);
    }
  }
  __builtin_amdgcn_sched_barrier(0);

  for (int tau = 0; tau < ntau; ++tau) {
    const int j0 = (part + 2 * tau) << 6;
    const int cur = tau & 1;
    // --- group A loads: vf (8 b128) + a0,a1 (2 dword) ---
    short8v vf[8];
#pragma unroll
    for (int db = 0; db < 4; ++db)
#pragma unroll
      for (int ks = 0; ks < 2; ++ks)
        vf[db * 2 + ks] = *(const short8v*)(vtg + (size_t)(bn * DHEAD + w * 64 + db * 16 + lm) * S_LEN + j0 + ks * 32 + l4 * 8);
    const float a0 = ag[(size_t)bn * S_LEN + j0 + cb0 * 16 + lm];
    const float a1 = ag[(size_t)bn * S_LEN + j0 + cb0 * 16 + 16 + lm];
    __builtin_amdgcn_sched_barrier(0);
    // --- stage next tile (8 gll16) ---
    const bool hasnext = (tau + 1 < ntau);
    if (hasnext) {
#pragma unroll
      for (int it = 0; it < 8; ++it) {
        const int row = it * 8 + w;
        gll16((const char*)kg + ((size_t)(b * S_LEN + j0 + 128 + row) * INNERD + n * DHEAD) * 2 + ((l * 16) ^ (w << 4)),
              (char*)Ks[cur ^ 1] + row * 1024);
      }
    }
    __builtin_amdgcn_sched_barrier(0);
    // wait: current stage done. queue = [stage_cur 8][vf+a 10][stage_next 0/8]
    if (hasnext) { asm volatile("s_waitcnt vmcnt(18)" ::: "memory"); }
    else         { asm volatile("s_waitcnt vmcnt(10)" ::: "memory"); }
    __builtin_amdgcn_sched_barrier(0);
    __builtin_amdgcn_s_barrier();
    // --- QK^T on Ks[cur] ---
    f32x4 s0 = (f32x4){0.f, 0.f, 0.f, 0.f}, s1 = (f32x4){0.f, 0.f, 0.f, 0.f};
    const char* kb0 = (const char*)Ks[cur] + (cb0 * 16 + lm) * 1024;
    const char* kb1 = (const char*)Ks[cur] + ((cb0 + 1) * 16 + lm) * 1024;
    __builtin_amdgcn_s_setprio(1);
#pragma unroll
    for (int ks = 0; ks < 16; ++ks) {
      const int off = (ks * 64 + l4 * 16) ^ ((lm & 7) << 4);
      const short8v b0 = *(const short8v*)(kb0 + off);
      const short8v b1 = *(const short8v*)(kb1 + off);
      s0 = MFMA_BF16(qf[ks], b0, s0);
      s1 = MFMA_BF16(qf[ks], b1, s1);
    }
    __builtin_amdgcn_s_setprio(0);
    // --- gate + causal mask + rowsum + P write ---
#pragma unroll
    for (int half = 0; half < 2; ++half) {
      const f32x4 sv = half ? s1 : s0;
      const float av = half ? a1 : a0;
      const int jl = (cb0 + half) * 16 + lm;
#pragma unroll
      for (int r = 0; r < 4; ++r) {
        const int il = rD + r;
        const float es = __expf(av - rm4[r]);
        const float p = (j0 + jl <= i0 + il) ? sv[r] * SCALE_QK * es : 0.0f;
        rs4[r] += p;
        *((unsigned short*)((char*)Ps + il * 128 + ((jl * 2) ^ ((il & 7) << 4)))) = f2bf(p);
      }
    }
    asm volatile("s_waitcnt lgkmcnt(0)" ::: "memory");
    __builtin_amdgcn_sched_barrier(0);
    __builtin_amdgcn_s_barrier();
    // --- PV ---
#pragma unroll
    for (int ks = 0; ks < 2; ++ks) {
      short8v pa[4];
#pragma unroll
      for (int rb = 0; rb < 4; ++rb)
        pa[rb] = *(const short8v*)((const char*)Ps + (rb * 16 + lm) * 128 + ((ks * 64 + l4 * 16) ^ ((lm & 7) << 4)));
      __builtin_amdgcn_s_setprio(1);
#pragma unroll
      for (int rb = 0; rb < 4; ++rb)
#pragma unroll
        for (int db = 0; db < 4; ++db)
          acc[rb * 4 + db] = MFMA_BF16(pa[rb], vf[db * 2 + ks], acc[rb * 4 + db]);
      __builtin_amdgcn_s_setprio(0);
    }
  }
  // rowsum combine via LDS (two waves share each 16-row block)
#pragma unroll
  for (int r = 0; r < 4; ++r) {
    float v2 = rs4[r];
    v2 += __shfl_xor(v2, 1, 64);
    v2 += __shfl_xor(v2, 2, 64);
    v2 += __shfl_xor(v2, 4, 64);
    v2 += __shfl_xor(v2, 8, 64);
    if (lm == 0) rsl[w][l4 * 4 + r] = v2;
  }
  asm volatile("s_waitcnt lgkmcnt(0)" ::: "memory");
  __builtin_amdgcn_s_barrier();
  if (tid < 64) {
    const int rblk = tid >> 4, rloc = tid & 15;
    rp[(size_t)bn * S_LEN + i0 + rblk * 16 + rloc] = rsl[rblk * 2][rloc] + rsl[rblk * 2 + 1][rloc];
  }
  // raw h partial store, bf16 (zero when loop empty)
#pragma unroll
  for (int rb = 0; rb < 4; ++rb)
#pragma unroll
    for (int db = 0; db < 4; ++db) {
      unsigned short* dst = hp + (size_t)(b * S_LEN + i0 + rb * 16 + l4 * 4) * INNERD + n * DHEAD + w * 64 + db * 16 + lm;
#pragma unroll
      for (int r = 0; r < 4; ++r) dst[(size_t)r * INNERD] = f2bf(acc[rb * 4 + db][r]);
    }
}

// ------- mhln: merge bf16 partials + norm + LN + conv-skip + swish(z), bf16 out -------
__global__ __launch_bounds__(256) void mhln_kernel(
    const unsigned short* __restrict__ h, const unsigned short* __restrict__ xm,
    const unsigned short* __restrict__ zb,
    const float* __restrict__ cw, const float* __restrict__ cbias,
    const float* __restrict__ rsumg, const float* __restrict__ eg,
    const float* __restrict__ normw, const float* __restrict__ skip,
    unsigned short* __restrict__ hstate) {
  const int bs = blockIdx.x, t = threadIdx.x;
  const int bb = bs >> 11, s = bs & (S_LEN - 1);
  const int n = t >> 6, lane = t & 63;
  const int cp0 = n * DHEAD + lane * 8;
  const size_t hb = (size_t)bs * INNERD + cp0;
  const size_t HOFF = (size_t)BATCH * S_LEN * INNERD;
  const int bn = bb * NHEAD + n;
  const float rsv = rsumg[(size_t)bn * S_LEN + s] + rsumg[(size_t)BATCH * NHEAD * S_LEN + bn * S_LEN + s];
  const float ev = eg[(size_t)bn * S_LEN + s];
  const float inorm = 1.0f / (fmaxf(fabsf(rsv), ev) + 1e-6f);
  const short8v h0 = *(const short8v*)(h + hb);
  const short8v h1 = *(const short8v*)(h + HOFF + hb);
  float vals[8];
#pragma unroll
  for (int u = 0; u < 8; ++u)
    vals[u] = (bf2f((unsigned short)h0[u]) + bf2f((unsigned short)h1[u])) * inorm;
  float sum = 0.0f;
#pragma unroll
  for (int u = 0; u < 8; ++u) sum += vals[u];
#pragma unroll
  for (int m = 32; m >= 1; m >>= 1) sum += __shfl_xor(sum, m, 64);
  const float mu = sum * (1.0f / 512.0f);
  float vs2 = 0.0f;
#pragma unroll
  for (int u = 0; u < 8; ++u) { const float d = vals[u] - mu; vs2 += d * d; }
#pragma unroll
  for (int m = 32; m >= 1; m >>= 1) vs2 += __shfl_xor(vs2, m, 64);
  const float rstd = rsqrtf(vs2 * (1.0f / 512.0f) + 1e-6f);
  float xa8[8];
  {
    float accv[8];
#pragma unroll
    for (int u = 0; u < 8; ++u) accv[u] = cbias[cp0 + u];
#pragma unroll
    for (int i2 = 0; i2 < 4; ++i2) {
      const int sj = s - 3 + i2;
      if (sj >= 0) {
        const short8v xv = *(const short8v*)(xm + (size_t)(bs - 3 + i2) * INNERD + cp0);
#pragma unroll
        for (int u = 0; u < 8; ++u)
          accv[u] += bf2f((unsigned short)xv[u]) * cw[i2 * INNERD + cp0 + u];
      }
    }
#pragma unroll
    for (int u = 0; u < 8; ++u) xa8[u] = swishf(accv[u]);
  }
  const short8v zv = *(const short8v*)(zb + (size_t)bs * INNERD + cp0);
  short8v o;
#pragma unroll
  for (int u = 0; u < 8; ++u) {
    const int cp = cp0 + u;
    const float hn = (vals[u] - mu) * rstd * normw[cp];
    const float z = bf2f((unsigned short)zv[u]);
    o[u] = (short)f2bf((hn + skip[cp] * xa8[u]) * swishf(z));
  }
  *(short8v*)(hstate + hb) = o;
}

extern "C" void kernel_launch(void* const* d_in, const int* in_sizes, int n_in,
                              void* d_out, int out_size, void* d_ws, size_t ws_size,
                              hipStream_t stream) {
  const float* x     = (const float*)d_in[0];
  const float* Wup   = (const float*)d_in[1];
  const float* cw    = (const float*)d_in[2];
  const float* cb    = (const float*)d_in[3];
  const float* Wq    = (const float*)d_in[4];
  const float* Wk    = (const float*)d_in[5];
  const float* Wv    = (const float*)d_in[6];
  const float* Wig   = (const float*)d_in[7];
  const float* big   = (const float*)d_in[8];
  const float* Wfg   = (const float*)d_in[9];
  const float* bfg   = (const float*)d_in[10];
  const float* normw = (const float*)d_in[11];
  const float* skip  = (const float*)d_in[12];
  const float* Wdown = (const float*)d_in[13];
  float* out = (float*)d_out;

  float* ws = (float*)d_ws;
  size_t off = 0;
  const size_t MR = (size_t)BATCH * S_LEN;  // 4096
  const size_t GSZ = (size_t)BATCH * NHEAD * S_LEN;  // 16384
  unsigned short* xm  = (unsigned short*)(ws + off); off += MR * INNERD / 2;
  unsigned short* zb  = (unsigned short*)(ws + off); off += MR * INNERD / 2;
  unsigned short* hraw = (unsigned short*)(ws + off); off += MR * INNERD;     // 2 bf16 partials
  unsigned short* qb  = (unsigned short*)(ws + off); off += MR * INNERD / 2;
  unsigned short* kb  = (unsigned short*)(ws + off); off += MR * INNERD / 2;
  unsigned short* vt  = (unsigned short*)(ws + off); off += MR * INNERD / 2;
  unsigned short* WdT = (unsigned short*)(ws + off); off += (size_t)2048 * 1024 / 2;
  float* igpre  = ws + off; off += GSZ;
  float* fgpre  = ws + off; off += GSZ;
  float* a_buf  = ws + off; off += GSZ;
  float* rm_buf = ws + off; off += GSZ;
  float* e_buf  = ws + off; off += GSZ;
  float* rsum   = ws + off; off += 2 * GSZ;          // two partials
  unsigned short* Wpk = (unsigned short*)(ws + off); off += 12 * 256 * 8 / 2;
  unsigned short* CgT = (unsigned short*)(ws + off); off += 16 * (size_t)INNERD / 2;
  if (ws_size < off * sizeof(float)) return;

  // aliases into dead regions
  unsigned short* vb     = hraw;                          // partial 0 region; dead before mlstm writes
  unsigned short* x_bf   = hraw + MR * INNERD;            // partial 1 region (u16 offset); dead before mlstm
  unsigned short* WupT   = vt;                            // dead before trv writes vt
  unsigned short* hstate = qb;                            // dead after mlstm

  setup_kernel<<<2433, 256, 0, stream>>>(x, Wup, Wdown, Wq, Wk, Wv, Wig, Wfg,
                                         x_bf, WupT, WdT, Wpk, CgT);
  gemm_bf16<128, 1><<<dim3(32, 32), 256, 0, stream>>>(x_bf, WupT, nullptr, xm, zb, 4096, 4096, 1024);
  headwise_kernel<<<4096, 256, 0, stream>>>(xm, Wpk, CgT, cw, cb, big, bfg,
                                            qb, kb, vb, igpre, fgpre);
  trv_kernel<<<dim3(16, 4, 8), 256, 0, stream>>>(vb, vt);
  scan_kernel<<<8, 256, 0, stream>>>(igpre, fgpre, a_buf, rm_buf, e_buf);
  mlstm_mfma<<<512, 512, 0, stream>>>(qb, kb, vt, a_buf, rm_buf, hraw, rsum);
  mhln_kernel<<<4096, 256, 0, stream>>>(hraw, xm, zb, cw, cb, rsum, e_buf, normw, skip, hstate);
  gemm_bf16<64, 0><<<dim3(16, 32), 256, 0, stream>>>(hstate, WdT, out, nullptr, nullptr, 4096, 1024, 2048);
}